// Round 4
// baseline (648.145 us; speedup 1.0000x reference)
//
#include <hip/hip_runtime.h>

// Problem constants (match reference)
#define B 32
#define S 32
#define N 128
#define U 64
#define E 2
#define NCLS 5

// One fused kernel. grid = 256 blocks (8 per batch element) x 512 threads.
// Each block owns 16 (b,n) rows: 8 waves x 2 rows; lane = feature column.
// h stays in registers for the whole network (row-local).
//
// Cross-block coupling: msg phase needs all of p[b] -> per-batch flag barrier.
// Barrier protocol (the R3 lesson): RELAXED agent-scope polls (scope bits give
// visibility without per-poll cache invalidates) + ONE acquire fence after the
// barrier; release fence + relaxed store on the signal side. Flags start as
// 0xAA poison != 1; each slot written once per launch -> no init needed.
// Block swizzle b=blockIdx&31 puts all 8 blocks of a batch on one XCD under
// round-robin placement (perf heuristic only; fences carry correctness).
// Deadlock-safe: 64KB LDS, 512thr => 1 block/CU, grid=256 = all resident.

__device__ __forceinline__ void flag_set(int* f) {
    __builtin_amdgcn_fence(__ATOMIC_RELEASE, "agent");
    __hip_atomic_store(f, 1, __ATOMIC_RELAXED, __HIP_MEMORY_SCOPE_AGENT);
}
__device__ __forceinline__ int flag_peek(const int* f) {
    return __hip_atomic_load(f, __ATOMIC_RELAXED, __HIP_MEMORY_SCOPE_AGENT);
}

__global__ __launch_bounds__(512) void k_all(
    const float* __restrict__ x, const int* __restrict__ lens,
    const float* __restrict__ A, const float* __restrict__ Wmsg,
    const float* __restrict__ bmsg, const float* __restrict__ Wg,
    const float* __restrict__ Ug, const float* __restrict__ bg,
    const float* __restrict__ fcw, const float* __restrict__ fcb,
    float* __restrict__ pA, float* __restrict__ pB,
    int* __restrict__ flags,      // [6][B][8]
    int* __restrict__ outflg,     // [B][8]
    float* __restrict__ partial,  // [B][8][NCLS]
    float* __restrict__ out) {
    __shared__ float ps[E * N * U];  // 64 KB: p[b] stage; reused as reduce buf
    int tid = threadIdx.x;
    int wave = tid >> 6, lane = tid & 63;
    int b = blockIdx.x & 31;   // XCD-local grouping: 8 blocks of b are == mod 8
    int j = blockIdx.x >> 5;
    int n0 = j * 16 + wave * 2;

    // ---- gather the relevant timestep rows into registers (persist all steps)
    int idx = lens[b] - 1;
    idx = idx < 0 ? 0 : (idx > S - 1 ? S - 1 : idx);
    const float* src = x + ((size_t)(b * S + idx) * N) * U;
    float hv0 = src[(size_t)(n0 + 0) * U + lane];
    float hv1 = src[(size_t)(n0 + 1) * U + lane];

    // ---- p0 = h @ Wmsg[l=0][e] for both edge types -> pA slice
    {
        const float* W0 = Wmsg;
        const float* W1 = Wmsg + U * U;
        float p00 = 0.f, p10 = 0.f, p01 = 0.f, p11 = 0.f;
        for (int u = 0; u < U; ++u) {
            float w0 = W0[u * U + lane], w1 = W1[u * U + lane];
            float h0 = __shfl(hv0, u, 64), h1 = __shfl(hv1, u, 64);
            p00 = fmaf(h0, w0, p00); p10 = fmaf(h1, w0, p10);
            p01 = fmaf(h0, w1, p01); p11 = fmaf(h1, w1, p11);
        }
        pA[(((size_t)b * E + 0) * N + n0 + 0) * U + lane] = p00;
        pA[(((size_t)b * E + 0) * N + n0 + 1) * U + lane] = p10;
        pA[(((size_t)b * E + 1) * N + n0 + 0) * U + lane] = p01;
        pA[(((size_t)b * E + 1) * N + n0 + 1) * U + lane] = p11;
    }
    __syncthreads();  // all waves' p stores issued+drained before signal
    if (tid == 0) flag_set(&flags[(0 * B + b) * 8 + j]);

    // ---- 6 propagation steps
    for (int step = 0; step < 6; ++step) {
        int l = (step >= 3) ? 1 : 0;
        const float* pin = (step & 1) ? pB : pA;
        float* pout = (step & 1) ? pA : pB;

        // wait for all 8 blocks of batch b to have written pin (relaxed polls)
        if (tid < 8) {
            const int* f = &flags[(step * B + b) * 8 + tid];
            while (flag_peek(f) != 1) __builtin_amdgcn_s_sleep(16);
        }
        __syncthreads();
        __builtin_amdgcn_fence(__ATOMIC_ACQUIRE, "agent");  // one inv, not per-poll

        // stage p[b] (all E*N rows) into LDS
        {
            const float4* s4 = (const float4*)(pin + (size_t)b * E * N * U);
            float4* d4 = (float4*)ps;
#pragma unroll
            for (int i = 0; i < 8; i++) d4[tid + i * 512] = s4[tid + i * 512];
        }
        __syncthreads();

        // message aggregation for our 2 rows: av = sum_e A_e[row,:] @ p_e + bm
        float bm = bmsg[l * U + lane];
        float av0 = bm, av1 = bm;
        for (int e = 0; e < E; ++e) {
            const float4* A0 = (const float4*)(A + (((size_t)b * E + e) * N + n0 + 0) * N);
            const float4* A1 = (const float4*)(A + (((size_t)b * E + e) * N + n0 + 1) * N);
            const float* pe = ps + e * N * U;
            for (int m4 = 0; m4 < N / 4; ++m4) {
                float4 a0 = A0[m4], a1 = A1[m4];
                float q0 = pe[(m4 * 4 + 0) * U + lane];
                float q1 = pe[(m4 * 4 + 1) * U + lane];
                float q2 = pe[(m4 * 4 + 2) * U + lane];
                float q3 = pe[(m4 * 4 + 3) * U + lane];
                av0 = fmaf(a0.x, q0, av0); av0 = fmaf(a0.y, q1, av0);
                av0 = fmaf(a0.z, q2, av0); av0 = fmaf(a0.w, q3, av0);
                av1 = fmaf(a1.x, q0, av1); av1 = fmaf(a1.y, q1, av1);
                av1 = fmaf(a1.z, q2, av1); av1 = fmaf(a1.w, q3, av1);
            }
        }

        // gate matmuls (lane = output column)
        const float* Wg0 = Wg + (size_t)l * 3 * U * U;
        const float* Wg1 = Wg0 + U * U;
        const float* Wg2 = Wg1 + U * U;
        const float* Ug0 = Ug + (size_t)l * 3 * U * U;
        const float* Ug1 = Ug0 + U * U;
        const float* Ug2 = Ug1 + U * U;
        float b0 = bg[(l * 3 + 0) * U + lane];
        float b1 = bg[(l * 3 + 1) * U + lane];
        float b2 = bg[(l * 3 + 2) * U + lane];
        float z0 = b0, z1 = b0, r0 = b1, r1 = b1, c0 = b2, c1 = b2;
        for (int u = 0; u < U; ++u) {
            float w0 = Wg0[u * U + lane], w1 = Wg1[u * U + lane], w2 = Wg2[u * U + lane];
            float g0 = Ug0[u * U + lane], g1 = Ug1[u * U + lane];
            float a0 = __shfl(av0, u, 64), a1 = __shfl(av1, u, 64);
            float h0 = __shfl(hv0, u, 64), h1 = __shfl(hv1, u, 64);
            z0 = fmaf(a0, w0, z0); z0 = fmaf(h0, g0, z0);
            z1 = fmaf(a1, w0, z1); z1 = fmaf(h1, g0, z1);
            r0 = fmaf(a0, w1, r0); r0 = fmaf(h0, g1, r0);
            r1 = fmaf(a1, w1, r1); r1 = fmaf(h1, g1, r1);
            c0 = fmaf(a0, w2, c0); c1 = fmaf(a1, w2, c1);
        }
        float rr0 = 1.f / (1.f + expf(-r0));
        float rr1 = 1.f / (1.f + expf(-r1));
        float rh0 = rr0 * hv0, rh1 = rr1 * hv1;
        for (int u = 0; u < U; ++u) {
            float g2 = Ug2[u * U + lane];
            c0 = fmaf(__shfl(rh0, u, 64), g2, c0);
            c1 = fmaf(__shfl(rh1, u, 64), g2, c1);
        }
        float zz0 = 1.f / (1.f + expf(-z0));
        float zz1 = 1.f / (1.f + expf(-z1));
        hv0 = (1.f - zz0) * hv0 + zz0 * tanhf(c0);
        hv1 = (1.f - zz1) * hv1 + zz1 * tanhf(c1);

        // p' = h' @ Wmsg[lnext] for next step
        if (step < 5) {
            int lnext = (step + 1 >= 3) ? 1 : 0;
            const float* W0 = Wmsg + (size_t)(lnext * E + 0) * U * U;
            const float* W1 = Wmsg + (size_t)(lnext * E + 1) * U * U;
            float p00 = 0.f, p10 = 0.f, p01 = 0.f, p11 = 0.f;
            for (int u = 0; u < U; ++u) {
                float w0 = W0[u * U + lane], w1 = W1[u * U + lane];
                float h0 = __shfl(hv0, u, 64), h1 = __shfl(hv1, u, 64);
                p00 = fmaf(h0, w0, p00); p10 = fmaf(h1, w0, p10);
                p01 = fmaf(h0, w1, p01); p11 = fmaf(h1, w1, p11);
            }
            pout[(((size_t)b * E + 0) * N + n0 + 0) * U + lane] = p00;
            pout[(((size_t)b * E + 0) * N + n0 + 1) * U + lane] = p10;
            pout[(((size_t)b * E + 1) * N + n0 + 0) * U + lane] = p01;
            pout[(((size_t)b * E + 1) * N + n0 + 1) * U + lane] = p11;
            __syncthreads();  // drain all waves' p' stores
            if (tid == 0) flag_set(&flags[((step + 1) * B + b) * 8 + j]);
        }
    }

    // ---- fused classification: block-partial of max_n relu(h') @ fc_w
    float lg0[NCLS], lg1[NCLS];
    float rv0 = hv0 > 0.f ? hv0 : 0.f;
    float rv1 = hv1 > 0.f ? hv1 : 0.f;
#pragma unroll
    for (int c = 0; c < NCLS; c++) {
        float w = fcw[lane * NCLS + c];
        lg0[c] = rv0 * w;
        lg1[c] = rv1 * w;
    }
#pragma unroll
    for (int off = 32; off; off >>= 1) {
#pragma unroll
        for (int c = 0; c < NCLS; c++) {
            lg0[c] += __shfl_xor(lg0[c], off, 64);
            lg1[c] += __shfl_xor(lg1[c], off, 64);
        }
    }
    __syncthreads();  // everyone done with ps (msg stage); reuse as reduce buf
    if (lane == 0) {
#pragma unroll
        for (int c = 0; c < NCLS; c++) ps[wave * NCLS + c] = fmaxf(lg0[c], lg1[c]);
    }
    __syncthreads();
    if (tid < NCLS) {
        float m = ps[tid];
        for (int w = 1; w < 8; ++w) m = fmaxf(m, ps[w * NCLS + tid]);
        partial[(size_t)(b * 8 + j) * NCLS + tid] = m;
    }
    __syncthreads();
    if (tid == 0) flag_set(&outflg[b * 8 + j]);

    // ---- block j==0 of each batch reduces the 8 partials and writes out
    if (j == 0 && wave == 0) {
        if (lane < 8) {
            const int* f = &outflg[b * 8 + lane];
            while (flag_peek(f) != 1) __builtin_amdgcn_s_sleep(16);
        }
        __builtin_amdgcn_fence(__ATOMIC_ACQUIRE, "agent");
        if (lane < NCLS) {
            float m = -3.4e38f;
            for (int jj = 0; jj < 8; ++jj)
                m = fmaxf(m, partial[(size_t)(b * 8 + jj) * NCLS + lane]);
            out[b * NCLS + lane] = m + fcb[lane];
        }
    }
}

// ---------------------------------------------------------------------------
extern "C" void kernel_launch(void* const* d_in, const int* in_sizes, int n_in,
                              void* d_out, int out_size, void* d_ws, size_t ws_size,
                              hipStream_t stream) {
    const float* x    = (const float*)d_in[0];
    const int*   lens = (const int*)d_in[1];
    const float* A    = (const float*)d_in[2];
    const float* Wmsg = (const float*)d_in[3];
    const float* bmsg = (const float*)d_in[4];
    const float* Wg   = (const float*)d_in[5];
    const float* Ug   = (const float*)d_in[6];
    const float* bg   = (const float*)d_in[7];
    const float* fcw  = (const float*)d_in[8];
    const float* fcb  = (const float*)d_in[9];
    float* out = (float*)d_out;

    float* pA      = (float*)d_ws;                   // [B][E][N][U]
    float* pB      = pA + (size_t)B * E * N * U;     // [B][E][N][U]
    float* partial = pB + (size_t)B * E * N * U;     // [B][8][NCLS]
    int*   flags   = (int*)(partial + (size_t)B * 8 * NCLS);  // [6][B][8]
    int*   outflg  = flags + 6 * B * 8;              // [B][8]

    k_all<<<B * 8, 512, 0, stream>>>(x, lens, A, Wmsg, bmsg, Wg, Ug, bg, fcw, fcb,
                                     pA, pB, flags, outflg, partial, out);
}

// Round 5
// 241.914 us; speedup vs baseline: 2.6792x; 2.6792x over previous
//
#include <hip/hip_runtime.h>

// Problem constants (match reference)
#define B 32
#define S 32
#define N 128
#define U 64
#define E 2
#define NCLS 5

// R5 structure: kernel-boundary sync only (R3/R4 lesson: cross-workgroup
// release/acquire on multi-XCD gfx950 = L2 wb/inv storms, ~100us/step).
// Reformulation: aggregate h, not p:  sum_m A_e[n,m] (h W_e)[m] =
// (sum_m A_e[n,m] h[m]) W_e  -> shared tensor is h (32KB/batch), p never
// materialized, step0 reads x directly (no producer), 7 dispatches total.
// h is double-buffered across dispatches (blocks write own rows, read all).
//
// grid = 256 blocks (8 per batch) x 512 threads; 8 waves x 2 rows; lane = col.

template <int FIRST, int LAST>
__global__ __launch_bounds__(512) void k_step(
    const float* __restrict__ x, const int* __restrict__ lens,
    const float* __restrict__ hin, float* __restrict__ hout,
    const float* __restrict__ A, const float* __restrict__ Wmsg,
    const float* __restrict__ bmsg, const float* __restrict__ Wg,
    const float* __restrict__ Ug, const float* __restrict__ bg,
    const float* __restrict__ fcw, float* __restrict__ partial, int l) {
    __shared__ float hs[N * U];  // 32 KB; reused as reduce buf on LAST
    int tid = threadIdx.x;
    int wave = tid >> 6, lane = tid & 63;
    int b = blockIdx.x >> 3;
    int j = blockIdx.x & 7;
    int n0 = j * 16 + wave * 2;

    // ---- stage h[b] (all N rows) into LDS: 2048 float4 over 512 threads
    {
        const float* src;
        if (FIRST) {
            int idx = lens[b] - 1;
            idx = idx < 0 ? 0 : (idx > S - 1 ? S - 1 : idx);
            src = x + (size_t)(b * S + idx) * N * U;
        } else {
            src = hin + (size_t)b * N * U;
        }
        const float4* s4 = (const float4*)src;
        float4* d4 = (float4*)hs;
#pragma unroll
        for (int i = 0; i < 4; i++) d4[tid + i * 512] = s4[tid + i * 512];
    }
    __syncthreads();

    float hv0 = hs[(n0 + 0) * U + lane];
    float hv1 = hs[(n0 + 1) * U + lane];

    // ---- aggregate h: s[row][e] = sum_m A[b,e,row,m] * hs[m][lane]
    float s00 = 0.f, s01 = 0.f, s10 = 0.f, s11 = 0.f;  // [row][e]
    {
        const float4* A00 = (const float4*)(A + (((size_t)b * E + 0) * N + n0 + 0) * N);
        const float4* A10 = (const float4*)(A + (((size_t)b * E + 0) * N + n0 + 1) * N);
        const float4* A01 = (const float4*)(A + (((size_t)b * E + 1) * N + n0 + 0) * N);
        const float4* A11 = (const float4*)(A + (((size_t)b * E + 1) * N + n0 + 1) * N);
        for (int m4 = 0; m4 < N / 4; ++m4) {
            float4 a00 = A00[m4], a10 = A10[m4], a01 = A01[m4], a11 = A11[m4];
            float q0 = hs[(m4 * 4 + 0) * U + lane];
            float q1 = hs[(m4 * 4 + 1) * U + lane];
            float q2 = hs[(m4 * 4 + 2) * U + lane];
            float q3 = hs[(m4 * 4 + 3) * U + lane];
            s00 = fmaf(a00.x, q0, s00); s00 = fmaf(a00.y, q1, s00);
            s00 = fmaf(a00.z, q2, s00); s00 = fmaf(a00.w, q3, s00);
            s10 = fmaf(a10.x, q0, s10); s10 = fmaf(a10.y, q1, s10);
            s10 = fmaf(a10.z, q2, s10); s10 = fmaf(a10.w, q3, s10);
            s01 = fmaf(a01.x, q0, s01); s01 = fmaf(a01.y, q1, s01);
            s01 = fmaf(a01.z, q2, s01); s01 = fmaf(a01.w, q3, s01);
            s11 = fmaf(a11.x, q0, s11); s11 = fmaf(a11.y, q1, s11);
            s11 = fmaf(a11.z, q2, s11); s11 = fmaf(a11.w, q3, s11);
        }
    }

    // ---- a[row] = sum_e s[row][e] @ Wmsg[l][e] + bmsg[l]
    float bm = bmsg[l * U + lane];
    float av0 = bm, av1 = bm;
    {
        const float* W0 = Wmsg + (size_t)(l * E + 0) * U * U;
        const float* W1 = Wmsg + (size_t)(l * E + 1) * U * U;
        for (int u = 0; u < U; ++u) {
            float w0 = W0[u * U + lane], w1 = W1[u * U + lane];
            av0 = fmaf(__shfl(s00, u, 64), w0, av0);
            av0 = fmaf(__shfl(s01, u, 64), w1, av0);
            av1 = fmaf(__shfl(s10, u, 64), w0, av1);
            av1 = fmaf(__shfl(s11, u, 64), w1, av1);
        }
    }

    // ---- gate matmuls (lane = output column)
    const float* Wg0 = Wg + (size_t)l * 3 * U * U;
    const float* Wg1 = Wg0 + U * U;
    const float* Wg2 = Wg1 + U * U;
    const float* Ug0 = Ug + (size_t)l * 3 * U * U;
    const float* Ug1 = Ug0 + U * U;
    const float* Ug2 = Ug1 + U * U;
    float b0 = bg[(l * 3 + 0) * U + lane];
    float b1 = bg[(l * 3 + 1) * U + lane];
    float b2 = bg[(l * 3 + 2) * U + lane];
    float z0 = b0, z1 = b0, r0 = b1, r1 = b1, c0 = b2, c1 = b2;
    for (int u = 0; u < U; ++u) {
        float w0 = Wg0[u * U + lane], w1 = Wg1[u * U + lane], w2 = Wg2[u * U + lane];
        float g0 = Ug0[u * U + lane], g1 = Ug1[u * U + lane];
        float a0 = __shfl(av0, u, 64), a1 = __shfl(av1, u, 64);
        float h0 = __shfl(hv0, u, 64), h1 = __shfl(hv1, u, 64);
        z0 = fmaf(a0, w0, z0); z0 = fmaf(h0, g0, z0);
        z1 = fmaf(a1, w0, z1); z1 = fmaf(h1, g0, z1);
        r0 = fmaf(a0, w1, r0); r0 = fmaf(h0, g1, r0);
        r1 = fmaf(a1, w1, r1); r1 = fmaf(h1, g1, r1);
        c0 = fmaf(a0, w2, c0); c1 = fmaf(a1, w2, c1);
    }
    float rr0 = 1.f / (1.f + expf(-r0));
    float rr1 = 1.f / (1.f + expf(-r1));
    float rh0 = rr0 * hv0, rh1 = rr1 * hv1;
    for (int u = 0; u < U; ++u) {
        float g2 = Ug2[u * U + lane];
        c0 = fmaf(__shfl(rh0, u, 64), g2, c0);
        c1 = fmaf(__shfl(rh1, u, 64), g2, c1);
    }
    float zz0 = 1.f / (1.f + expf(-z0));
    float zz1 = 1.f / (1.f + expf(-z1));
    float hn0 = (1.f - zz0) * hv0 + zz0 * tanhf(c0);
    float hn1 = (1.f - zz1) * hv1 + zz1 * tanhf(c1);

    if (!LAST) {
        hout[((size_t)b * N + n0 + 0) * U + lane] = hn0;
        hout[((size_t)b * N + n0 + 1) * U + lane] = hn1;
    } else {
        // fused classification partial: max over our 16 rows of relu(h')@fc_w
        float lg0[NCLS], lg1[NCLS];
        float rv0 = hn0 > 0.f ? hn0 : 0.f;
        float rv1 = hn1 > 0.f ? hn1 : 0.f;
#pragma unroll
        for (int c = 0; c < NCLS; c++) {
            float w = fcw[lane * NCLS + c];
            lg0[c] = rv0 * w;
            lg1[c] = rv1 * w;
        }
#pragma unroll
        for (int off = 32; off; off >>= 1) {
#pragma unroll
            for (int c = 0; c < NCLS; c++) {
                lg0[c] += __shfl_xor(lg0[c], off, 64);
                lg1[c] += __shfl_xor(lg1[c], off, 64);
            }
        }
        __syncthreads();  // all waves done reading hs; reuse as reduce buf
        if (lane == 0) {
#pragma unroll
            for (int c = 0; c < NCLS; c++) hs[wave * NCLS + c] = fmaxf(lg0[c], lg1[c]);
        }
        __syncthreads();
        if (tid < NCLS) {
            float m = hs[tid];
            for (int w = 1; w < 8; ++w) m = fmaxf(m, hs[w * NCLS + tid]);
            partial[(size_t)(b * 8 + j) * NCLS + tid] = m;
        }
    }
}

// ---------------------------------------------------------------------------
// k_final: out[b][c] = max over 8 block-partials + fc_b
__global__ void k_final(const float* __restrict__ partial, const float* __restrict__ fcb,
                        float* __restrict__ out) {
    int b = blockIdx.x, c = threadIdx.x;
    if (c < NCLS) {
        float m = -3.4e38f;
        for (int jj = 0; jj < 8; ++jj)
            m = fmaxf(m, partial[(size_t)(b * 8 + jj) * NCLS + c]);
        out[b * NCLS + c] = m + fcb[c];
    }
}

// ---------------------------------------------------------------------------
extern "C" void kernel_launch(void* const* d_in, const int* in_sizes, int n_in,
                              void* d_out, int out_size, void* d_ws, size_t ws_size,
                              hipStream_t stream) {
    const float* x    = (const float*)d_in[0];
    const int*   lens = (const int*)d_in[1];
    const float* A    = (const float*)d_in[2];
    const float* Wmsg = (const float*)d_in[3];
    const float* bmsg = (const float*)d_in[4];
    const float* Wg   = (const float*)d_in[5];
    const float* Ug   = (const float*)d_in[6];
    const float* bg   = (const float*)d_in[7];
    const float* fcw  = (const float*)d_in[8];
    const float* fcb  = (const float*)d_in[9];
    float* out = (float*)d_out;

    float* hA      = (float*)d_ws;                   // [B][N][U]
    float* hB      = hA + (size_t)B * N * U;         // [B][N][U]
    float* partial = hB + (size_t)B * N * U;         // [B][8][NCLS]

    // steps 0-2: layer 0; steps 3-5: layer 1
    k_step<1, 0><<<256, 512, 0, stream>>>(x, lens, nullptr, hA, A, Wmsg, bmsg, Wg, Ug, bg, fcw, partial, 0);
    k_step<0, 0><<<256, 512, 0, stream>>>(x, lens, hA, hB, A, Wmsg, bmsg, Wg, Ug, bg, fcw, partial, 0);
    k_step<0, 0><<<256, 512, 0, stream>>>(x, lens, hB, hA, A, Wmsg, bmsg, Wg, Ug, bg, fcw, partial, 0);
    k_step<0, 0><<<256, 512, 0, stream>>>(x, lens, hA, hB, A, Wmsg, bmsg, Wg, Ug, bg, fcw, partial, 1);
    k_step<0, 0><<<256, 512, 0, stream>>>(x, lens, hB, hA, A, Wmsg, bmsg, Wg, Ug, bg, fcw, partial, 1);
    k_step<0, 1><<<256, 512, 0, stream>>>(x, lens, hA, hB, A, Wmsg, bmsg, Wg, Ug, bg, fcw, partial, 1);
    k_final<<<B, 64, 0, stream>>>(partial, fcb, out);
}

// Round 6
// 218.573 us; speedup vs baseline: 2.9654x; 1.1068x over previous
//
#include <hip/hip_runtime.h>

// Problem constants (match reference)
#define B 32
#define S 32
#define N 128
#define U 64
#define E 2
#define NCLS 5

// R6: same 7-dispatch structure as R5 (kernel-boundary sync only; 6 sequential
// all-to-all rounds is the algorithmic minimum depth). Per-kernel optimization:
// k_step was LDS-pipe-bound via ~640 ds_bpermute (__shfl u-broadcasts). Each
// broadcast value is wave-uniform per row and rows are wave-private, so we
// route broadcasts through a tiny wave-local LDS buffer bc[16][U]: write own
// value once, read back with same-address ds_read_b128 (free broadcast, 4 u
// per instr). No barriers needed for bc (strictly wave-private rows; compiler
// orders aliasing ds ops conservatively). Fast overflow-safe sigmoid/tanh.
//
// grid = 256 blocks (8 per batch) x 512 threads; 8 waves x 2 rows; lane = col.

__device__ __forceinline__ float sigmoid_f(float x) {
    // 1/(1+e^-x); e^-x -> inf for very negative x gives 0, 0 for large x gives 1.
    return __fdividef(1.f, 1.f + __expf(-x));
}
__device__ __forceinline__ float tanh_f(float x) {
    // overflow-safe: t = e^{-2|x|} in (0,1]
    float t = __expf(-2.f * fabsf(x));
    float y = __fdividef(1.f - t, 1.f + t);
    return copysignf(y, x);
}

template <int FIRST, int LAST>
__global__ __launch_bounds__(512) void k_step(
    const float* __restrict__ x, const int* __restrict__ lens,
    const float* __restrict__ hin, float* __restrict__ hout,
    const float* __restrict__ A, const float* __restrict__ Wmsg,
    const float* __restrict__ bmsg, const float* __restrict__ Wg,
    const float* __restrict__ Ug, const float* __restrict__ bg,
    const float* __restrict__ fcw, float* __restrict__ partial, int l) {
    __shared__ float hs[N * U];   // 32 KB: h[b] staged (all rows)
    __shared__ float bc[16 * U];  // 4 KB: wave-local broadcast buffer (own 2 rows)
    int tid = threadIdx.x;
    int wave = tid >> 6, lane = tid & 63;
    int b = blockIdx.x >> 3;
    int j = blockIdx.x & 7;
    int n0 = j * 16 + wave * 2;   // global row base (2 rows per wave)
    int r0 = wave * 2;            // local row base in bc

    // ---- stage h[b] (all N rows) into LDS: 2048 float4 over 512 threads
    {
        const float* src;
        if (FIRST) {
            int idx = lens[b] - 1;
            idx = idx < 0 ? 0 : (idx > S - 1 ? S - 1 : idx);
            src = x + (size_t)(b * S + idx) * N * U;
        } else {
            src = hin + (size_t)b * N * U;
        }
        const float4* s4 = (const float4*)src;
        float4* d4 = (float4*)hs;
#pragma unroll
        for (int i = 0; i < 4; i++) d4[tid + i * 512] = s4[tid + i * 512];
    }
    __syncthreads();

    float hv0 = hs[(n0 + 0) * U + lane];
    float hv1 = hs[(n0 + 1) * U + lane];

    // ---- aggregate h: s[row][e] = sum_m A[b,e,row,m] * hs[m][lane]
    float s00 = 0.f, s01 = 0.f, s10 = 0.f, s11 = 0.f;  // [row][e]
    {
        const float4* A00 = (const float4*)(A + (((size_t)b * E + 0) * N + n0 + 0) * N);
        const float4* A10 = (const float4*)(A + (((size_t)b * E + 0) * N + n0 + 1) * N);
        const float4* A01 = (const float4*)(A + (((size_t)b * E + 1) * N + n0 + 0) * N);
        const float4* A11 = (const float4*)(A + (((size_t)b * E + 1) * N + n0 + 1) * N);
        for (int m4 = 0; m4 < N / 4; ++m4) {
            float4 a00 = A00[m4], a10 = A10[m4], a01 = A01[m4], a11 = A11[m4];
            float q0 = hs[(m4 * 4 + 0) * U + lane];
            float q1 = hs[(m4 * 4 + 1) * U + lane];
            float q2 = hs[(m4 * 4 + 2) * U + lane];
            float q3 = hs[(m4 * 4 + 3) * U + lane];
            s00 = fmaf(a00.x, q0, s00); s00 = fmaf(a00.y, q1, s00);
            s00 = fmaf(a00.z, q2, s00); s00 = fmaf(a00.w, q3, s00);
            s10 = fmaf(a10.x, q0, s10); s10 = fmaf(a10.y, q1, s10);
            s10 = fmaf(a10.z, q2, s10); s10 = fmaf(a10.w, q3, s10);
            s01 = fmaf(a01.x, q0, s01); s01 = fmaf(a01.y, q1, s01);
            s01 = fmaf(a01.z, q2, s01); s01 = fmaf(a01.w, q3, s01);
            s11 = fmaf(a11.x, q0, s11); s11 = fmaf(a11.y, q1, s11);
            s11 = fmaf(a11.z, q2, s11); s11 = fmaf(a11.w, q3, s11);
        }
    }

    // ---- a[row] = sum_e s[row][e] @ Wmsg[l][e] + bmsg[l]  (bc broadcast)
    float bm = bmsg[l * U + lane];
    float av0 = bm, av1 = bm;
    {
        const float* W0 = Wmsg + (size_t)(l * E + 0) * U * U;
        const float* W1 = Wmsg + (size_t)(l * E + 1) * U * U;
        bc[(r0 + 0) * U + lane] = s00;
        bc[(r0 + 1) * U + lane] = s10;
        for (int u4 = 0; u4 < U; u4 += 4) {
            float sa[4], sb[4];
            *(float4*)sa = *(const float4*)(bc + (r0 + 0) * U + u4);
            *(float4*)sb = *(const float4*)(bc + (r0 + 1) * U + u4);
#pragma unroll
            for (int k = 0; k < 4; ++k) {
                float w = W0[(u4 + k) * U + lane];
                av0 = fmaf(sa[k], w, av0);
                av1 = fmaf(sb[k], w, av1);
            }
        }
        bc[(r0 + 0) * U + lane] = s01;  // wave-local WAR on bc: in-order DS pipe
        bc[(r0 + 1) * U + lane] = s11;
        for (int u4 = 0; u4 < U; u4 += 4) {
            float sa[4], sb[4];
            *(float4*)sa = *(const float4*)(bc + (r0 + 0) * U + u4);
            *(float4*)sb = *(const float4*)(bc + (r0 + 1) * U + u4);
#pragma unroll
            for (int k = 0; k < 4; ++k) {
                float w = W1[(u4 + k) * U + lane];
                av0 = fmaf(sa[k], w, av0);
                av1 = fmaf(sb[k], w, av1);
            }
        }
    }

    // ---- gate matmuls (lane = output column v); a,h broadcasts via bc/hs b128
    const float* Wg0 = Wg + (size_t)l * 3 * U * U;
    const float* Wg1 = Wg0 + U * U;
    const float* Wg2 = Wg1 + U * U;
    const float* Ug0 = Ug + (size_t)l * 3 * U * U;
    const float* Ug1 = Ug0 + U * U;
    const float* Ug2 = Ug1 + U * U;
    float accz0 = bg[(l * 3 + 0) * U + lane], accz1 = accz0;
    float accr0 = bg[(l * 3 + 1) * U + lane], accr1 = accr0;
    float accc0 = bg[(l * 3 + 2) * U + lane], accc1 = accc0;
    bc[(r0 + 0) * U + lane] = av0;
    bc[(r0 + 1) * U + lane] = av1;
    for (int u4 = 0; u4 < U; u4 += 4) {
        float a0[4], a1[4], h0[4], h1[4];
        *(float4*)a0 = *(const float4*)(bc + (r0 + 0) * U + u4);
        *(float4*)a1 = *(const float4*)(bc + (r0 + 1) * U + u4);
        *(float4*)h0 = *(const float4*)(hs + (n0 + 0) * U + u4);
        *(float4*)h1 = *(const float4*)(hs + (n0 + 1) * U + u4);
#pragma unroll
        for (int k = 0; k < 4; ++k) {
            int u = u4 + k;
            float w0 = Wg0[u * U + lane], w1 = Wg1[u * U + lane], w2 = Wg2[u * U + lane];
            float g0 = Ug0[u * U + lane], g1 = Ug1[u * U + lane];
            accz0 = fmaf(a0[k], w0, accz0); accz0 = fmaf(h0[k], g0, accz0);
            accz1 = fmaf(a1[k], w0, accz1); accz1 = fmaf(h1[k], g0, accz1);
            accr0 = fmaf(a0[k], w1, accr0); accr0 = fmaf(h0[k], g1, accr0);
            accr1 = fmaf(a1[k], w1, accr1); accr1 = fmaf(h1[k], g1, accr1);
            accc0 = fmaf(a0[k], w2, accc0);
            accc1 = fmaf(a1[k], w2, accc1);
        }
    }
    float rg0 = sigmoid_f(accr0), rg1 = sigmoid_f(accr1);
    float rh0 = rg0 * hv0, rh1 = rg1 * hv1;
    bc[(r0 + 0) * U + lane] = rh0;  // overwrite av (fully consumed; wave-local)
    bc[(r0 + 1) * U + lane] = rh1;
    for (int u4 = 0; u4 < U; u4 += 4) {
        float p0[4], p1[4];
        *(float4*)p0 = *(const float4*)(bc + (r0 + 0) * U + u4);
        *(float4*)p1 = *(const float4*)(bc + (r0 + 1) * U + u4);
#pragma unroll
        for (int k = 0; k < 4; ++k) {
            float g2 = Ug2[(u4 + k) * U + lane];
            accc0 = fmaf(p0[k], g2, accc0);
            accc1 = fmaf(p1[k], g2, accc1);
        }
    }
    float zg0 = sigmoid_f(accz0), zg1 = sigmoid_f(accz1);
    float hn0 = (1.f - zg0) * hv0 + zg0 * tanh_f(accc0);
    float hn1 = (1.f - zg1) * hv1 + zg1 * tanh_f(accc1);

    if (!LAST) {
        hout[((size_t)b * N + n0 + 0) * U + lane] = hn0;
        hout[((size_t)b * N + n0 + 1) * U + lane] = hn1;
    } else {
        // fused classification partial: max over our 16 rows of relu(h')@fc_w
        float lg0[NCLS], lg1[NCLS];
        float rv0 = hn0 > 0.f ? hn0 : 0.f;
        float rv1 = hn1 > 0.f ? hn1 : 0.f;
#pragma unroll
        for (int c = 0; c < NCLS; c++) {
            float w = fcw[lane * NCLS + c];
            lg0[c] = rv0 * w;
            lg1[c] = rv1 * w;
        }
#pragma unroll
        for (int off = 32; off; off >>= 1) {
#pragma unroll
            for (int c = 0; c < NCLS; c++) {
                lg0[c] += __shfl_xor(lg0[c], off, 64);
                lg1[c] += __shfl_xor(lg1[c], off, 64);
            }
        }
        __syncthreads();  // all waves past bc/hs use; reuse bc as reduce buffer
        if (lane == 0) {
#pragma unroll
            for (int c = 0; c < NCLS; c++) bc[wave * NCLS + c] = fmaxf(lg0[c], lg1[c]);
        }
        __syncthreads();
        if (tid < NCLS) {
            float m = bc[tid];
            for (int w = 1; w < 8; ++w) m = fmaxf(m, bc[w * NCLS + tid]);
            partial[(size_t)(b * 8 + j) * NCLS + tid] = m;
        }
    }
}

// ---------------------------------------------------------------------------
// k_final: out[b][c] = max over 8 block-partials + fc_b
__global__ void k_final(const float* __restrict__ partial, const float* __restrict__ fcb,
                        float* __restrict__ out) {
    int b = blockIdx.x, c = threadIdx.x;
    if (c < NCLS) {
        float m = -3.4e38f;
        for (int jj = 0; jj < 8; ++jj)
            m = fmaxf(m, partial[(size_t)(b * 8 + jj) * NCLS + c]);
        out[b * NCLS + c] = m + fcb[c];
    }
}

// ---------------------------------------------------------------------------
extern "C" void kernel_launch(void* const* d_in, const int* in_sizes, int n_in,
                              void* d_out, int out_size, void* d_ws, size_t ws_size,
                              hipStream_t stream) {
    const float* x    = (const float*)d_in[0];
    const int*   lens = (const int*)d_in[1];
    const float* A    = (const float*)d_in[2];
    const float* Wmsg = (const float*)d_in[3];
    const float* bmsg = (const float*)d_in[4];
    const float* Wg   = (const float*)d_in[5];
    const float* Ug   = (const float*)d_in[6];
    const float* bg   = (const float*)d_in[7];
    const float* fcw  = (const float*)d_in[8];
    const float* fcb  = (const float*)d_in[9];
    float* out = (float*)d_out;

    float* hA      = (float*)d_ws;                   // [B][N][U]
    float* hB      = hA + (size_t)B * N * U;         // [B][N][U]
    float* partial = hB + (size_t)B * N * U;         // [B][8][NCLS]

    // steps 0-2: layer 0; steps 3-5: layer 1
    k_step<1, 0><<<256, 512, 0, stream>>>(x, lens, nullptr, hA, A, Wmsg, bmsg, Wg, Ug, bg, fcw, partial, 0);
    k_step<0, 0><<<256, 512, 0, stream>>>(x, lens, hA, hB, A, Wmsg, bmsg, Wg, Ug, bg, fcw, partial, 0);
    k_step<0, 0><<<256, 512, 0, stream>>>(x, lens, hB, hA, A, Wmsg, bmsg, Wg, Ug, bg, fcw, partial, 0);
    k_step<0, 0><<<256, 512, 0, stream>>>(x, lens, hA, hB, A, Wmsg, bmsg, Wg, Ug, bg, fcw, partial, 1);
    k_step<0, 0><<<256, 512, 0, stream>>>(x, lens, hB, hA, A, Wmsg, bmsg, Wg, Ug, bg, fcw, partial, 1);
    k_step<0, 1><<<256, 512, 0, stream>>>(x, lens, hA, hB, A, Wmsg, bmsg, Wg, Ug, bg, fcw, partial, 1);
    k_final<<<B, 64, 0, stream>>>(partial, fcb, out);
}

// Round 7
// 214.242 us; speedup vs baseline: 3.0253x; 1.0202x over previous
//
#include <hip/hip_runtime.h>

// Problem constants (match reference)
#define B 32
#define S 32
#define N 128
#define U 64
#define E 2
#define NCLS 5

// R7: same 7-dispatch structure (kernel-boundary sync only; 6 sequential
// all-to-all rounds = algorithmic min depth; R3/R4: in-kernel cross-XCD sync
// ~90us/step, dead end). Change vs R6: occupancy. 256-thr blocks, 16 blocks
// per batch (grid 512) -> 2 blocks/CU (LDS 34KB, VGPR<=128), so one block's
// staging/barrier stalls overlap the co-resident block's FMA issue. Keeps the
// R6 LDS-broadcast trick (wave-private bc rows, same-address ds_read_b128)
// and fast overflow-safe sigmoid/tanh.
//
// Each block: 8 rows of one batch (4 waves x 2 rows); lane = feature column.

__device__ __forceinline__ float sigmoid_f(float x) {
    return __fdividef(1.f, 1.f + __expf(-x));
}
__device__ __forceinline__ float tanh_f(float x) {
    float t = __expf(-2.f * fabsf(x));
    float y = __fdividef(1.f - t, 1.f + t);
    return copysignf(y, x);
}

template <int FIRST, int LAST>
__global__ __launch_bounds__(256) void k_step(
    const float* __restrict__ x, const int* __restrict__ lens,
    const float* __restrict__ hin, float* __restrict__ hout,
    const float* __restrict__ A, const float* __restrict__ Wmsg,
    const float* __restrict__ bmsg, const float* __restrict__ Wg,
    const float* __restrict__ Ug, const float* __restrict__ bg,
    const float* __restrict__ fcw, float* __restrict__ partial, int l) {
    __shared__ float hs[N * U];  // 32 KB: h[b] staged (all rows)
    __shared__ float bc[8 * U];  // 2 KB: wave-local broadcast buffer (own 2 rows)
    int tid = threadIdx.x;
    int wave = tid >> 6, lane = tid & 63;
    int b = blockIdx.x >> 4;
    int j = blockIdx.x & 15;
    int n0 = j * 8 + wave * 2;  // global row base (2 rows per wave)
    int r0 = wave * 2;          // local row base in bc

    // ---- stage h[b] (all N rows) into LDS: 2048 float4 over 256 threads
    {
        const float* src;
        if (FIRST) {
            int idx = lens[b] - 1;
            idx = idx < 0 ? 0 : (idx > S - 1 ? S - 1 : idx);
            src = x + (size_t)(b * S + idx) * N * U;
        } else {
            src = hin + (size_t)b * N * U;
        }
        const float4* s4 = (const float4*)src;
        float4* d4 = (float4*)hs;
#pragma unroll
        for (int i = 0; i < 8; i++) d4[tid + i * 256] = s4[tid + i * 256];
    }
    __syncthreads();

    float hv0 = hs[(n0 + 0) * U + lane];
    float hv1 = hs[(n0 + 1) * U + lane];

    // ---- aggregate h: s[row][e] = sum_m A[b,e,row,m] * hs[m][lane]
    float s00 = 0.f, s01 = 0.f, s10 = 0.f, s11 = 0.f;  // [row][e]
    {
        const float4* A00 = (const float4*)(A + (((size_t)b * E + 0) * N + n0 + 0) * N);
        const float4* A10 = (const float4*)(A + (((size_t)b * E + 0) * N + n0 + 1) * N);
        const float4* A01 = (const float4*)(A + (((size_t)b * E + 1) * N + n0 + 0) * N);
        const float4* A11 = (const float4*)(A + (((size_t)b * E + 1) * N + n0 + 1) * N);
        for (int m4 = 0; m4 < N / 4; ++m4) {
            float4 a00 = A00[m4], a10 = A10[m4], a01 = A01[m4], a11 = A11[m4];
            float q0 = hs[(m4 * 4 + 0) * U + lane];
            float q1 = hs[(m4 * 4 + 1) * U + lane];
            float q2 = hs[(m4 * 4 + 2) * U + lane];
            float q3 = hs[(m4 * 4 + 3) * U + lane];
            s00 = fmaf(a00.x, q0, s00); s00 = fmaf(a00.y, q1, s00);
            s00 = fmaf(a00.z, q2, s00); s00 = fmaf(a00.w, q3, s00);
            s10 = fmaf(a10.x, q0, s10); s10 = fmaf(a10.y, q1, s10);
            s10 = fmaf(a10.z, q2, s10); s10 = fmaf(a10.w, q3, s10);
            s01 = fmaf(a01.x, q0, s01); s01 = fmaf(a01.y, q1, s01);
            s01 = fmaf(a01.z, q2, s01); s01 = fmaf(a01.w, q3, s01);
            s11 = fmaf(a11.x, q0, s11); s11 = fmaf(a11.y, q1, s11);
            s11 = fmaf(a11.z, q2, s11); s11 = fmaf(a11.w, q3, s11);
        }
    }

    // ---- a[row] = sum_e s[row][e] @ Wmsg[l][e] + bmsg[l]  (bc broadcast)
    float bm = bmsg[l * U + lane];
    float av0 = bm, av1 = bm;
    {
        const float* W0 = Wmsg + (size_t)(l * E + 0) * U * U;
        const float* W1 = Wmsg + (size_t)(l * E + 1) * U * U;
        bc[(r0 + 0) * U + lane] = s00;
        bc[(r0 + 1) * U + lane] = s10;
        for (int u4 = 0; u4 < U; u4 += 4) {
            float sa[4], sb[4];
            *(float4*)sa = *(const float4*)(bc + (r0 + 0) * U + u4);
            *(float4*)sb = *(const float4*)(bc + (r0 + 1) * U + u4);
#pragma unroll
            for (int k = 0; k < 4; ++k) {
                float w = W0[(u4 + k) * U + lane];
                av0 = fmaf(sa[k], w, av0);
                av1 = fmaf(sb[k], w, av1);
            }
        }
        bc[(r0 + 0) * U + lane] = s01;  // wave-local WAR on bc: in-order DS pipe
        bc[(r0 + 1) * U + lane] = s11;
        for (int u4 = 0; u4 < U; u4 += 4) {
            float sa[4], sb[4];
            *(float4*)sa = *(const float4*)(bc + (r0 + 0) * U + u4);
            *(float4*)sb = *(const float4*)(bc + (r0 + 1) * U + u4);
#pragma unroll
            for (int k = 0; k < 4; ++k) {
                float w = W1[(u4 + k) * U + lane];
                av0 = fmaf(sa[k], w, av0);
                av1 = fmaf(sb[k], w, av1);
            }
        }
    }

    // ---- gate matmuls (lane = output column v); a,h broadcasts via bc/hs b128
    const float* Wg0 = Wg + (size_t)l * 3 * U * U;
    const float* Wg1 = Wg0 + U * U;
    const float* Wg2 = Wg1 + U * U;
    const float* Ug0 = Ug + (size_t)l * 3 * U * U;
    const float* Ug1 = Ug0 + U * U;
    const float* Ug2 = Ug1 + U * U;
    float accz0 = bg[(l * 3 + 0) * U + lane], accz1 = accz0;
    float accr0 = bg[(l * 3 + 1) * U + lane], accr1 = accr0;
    float accc0 = bg[(l * 3 + 2) * U + lane], accc1 = accc0;
    bc[(r0 + 0) * U + lane] = av0;
    bc[(r0 + 1) * U + lane] = av1;
    for (int u4 = 0; u4 < U; u4 += 4) {
        float a0[4], a1[4], h0[4], h1[4];
        *(float4*)a0 = *(const float4*)(bc + (r0 + 0) * U + u4);
        *(float4*)a1 = *(const float4*)(bc + (r0 + 1) * U + u4);
        *(float4*)h0 = *(const float4*)(hs + (n0 + 0) * U + u4);
        *(float4*)h1 = *(const float4*)(hs + (n0 + 1) * U + u4);
#pragma unroll
        for (int k = 0; k < 4; ++k) {
            int u = u4 + k;
            float w0 = Wg0[u * U + lane], w1 = Wg1[u * U + lane], w2 = Wg2[u * U + lane];
            float g0 = Ug0[u * U + lane], g1 = Ug1[u * U + lane];
            accz0 = fmaf(a0[k], w0, accz0); accz0 = fmaf(h0[k], g0, accz0);
            accz1 = fmaf(a1[k], w0, accz1); accz1 = fmaf(h1[k], g0, accz1);
            accr0 = fmaf(a0[k], w1, accr0); accr0 = fmaf(h0[k], g1, accr0);
            accr1 = fmaf(a1[k], w1, accr1); accr1 = fmaf(h1[k], g1, accr1);
            accc0 = fmaf(a0[k], w2, accc0);
            accc1 = fmaf(a1[k], w2, accc1);
        }
    }
    float rg0 = sigmoid_f(accr0), rg1 = sigmoid_f(accr1);
    float rh0 = rg0 * hv0, rh1 = rg1 * hv1;
    bc[(r0 + 0) * U + lane] = rh0;  // overwrite av (fully consumed; wave-local)
    bc[(r0 + 1) * U + lane] = rh1;
    for (int u4 = 0; u4 < U; u4 += 4) {
        float p0[4], p1[4];
        *(float4*)p0 = *(const float4*)(bc + (r0 + 0) * U + u4);
        *(float4*)p1 = *(const float4*)(bc + (r0 + 1) * U + u4);
#pragma unroll
        for (int k = 0; k < 4; ++k) {
            float g2 = Ug2[(u4 + k) * U + lane];
            accc0 = fmaf(p0[k], g2, accc0);
            accc1 = fmaf(p1[k], g2, accc1);
        }
    }
    float zg0 = sigmoid_f(accz0), zg1 = sigmoid_f(accz1);
    float hn0 = (1.f - zg0) * hv0 + zg0 * tanh_f(accc0);
    float hn1 = (1.f - zg1) * hv1 + zg1 * tanh_f(accc1);

    if (!LAST) {
        hout[((size_t)b * N + n0 + 0) * U + lane] = hn0;
        hout[((size_t)b * N + n0 + 1) * U + lane] = hn1;
    } else {
        // fused classification partial: max over our 8 rows of relu(h')@fc_w
        float lg0[NCLS], lg1[NCLS];
        float rv0 = hn0 > 0.f ? hn0 : 0.f;
        float rv1 = hn1 > 0.f ? hn1 : 0.f;
#pragma unroll
        for (int c = 0; c < NCLS; c++) {
            float w = fcw[lane * NCLS + c];
            lg0[c] = rv0 * w;
            lg1[c] = rv1 * w;
        }
#pragma unroll
        for (int off = 32; off; off >>= 1) {
#pragma unroll
            for (int c = 0; c < NCLS; c++) {
                lg0[c] += __shfl_xor(lg0[c], off, 64);
                lg1[c] += __shfl_xor(lg1[c], off, 64);
            }
        }
        __syncthreads();  // all waves past bc/hs use; reuse bc as reduce buffer
        if (lane == 0) {
#pragma unroll
            for (int c = 0; c < NCLS; c++) bc[wave * NCLS + c] = fmaxf(lg0[c], lg1[c]);
        }
        __syncthreads();
        if (tid < NCLS) {
            float m = bc[tid];
            for (int w = 1; w < 4; ++w) m = fmaxf(m, bc[w * NCLS + tid]);
            partial[(size_t)(b * 16 + j) * NCLS + tid] = m;
        }
    }
}

// ---------------------------------------------------------------------------
// k_final: out[b][c] = max over 16 block-partials + fc_b
__global__ void k_final(const float* __restrict__ partial, const float* __restrict__ fcb,
                        float* __restrict__ out) {
    int b = blockIdx.x, c = threadIdx.x;
    if (c < NCLS) {
        float m = -3.4e38f;
        for (int jj = 0; jj < 16; ++jj)
            m = fmaxf(m, partial[(size_t)(b * 16 + jj) * NCLS + c]);
        out[b * NCLS + c] = m + fcb[c];
    }
}

// ---------------------------------------------------------------------------
extern "C" void kernel_launch(void* const* d_in, const int* in_sizes, int n_in,
                              void* d_out, int out_size, void* d_ws, size_t ws_size,
                              hipStream_t stream) {
    const float* x    = (const float*)d_in[0];
    const int*   lens = (const int*)d_in[1];
    const float* A    = (const float*)d_in[2];
    const float* Wmsg = (const float*)d_in[3];
    const float* bmsg = (const float*)d_in[4];
    const float* Wg   = (const float*)d_in[5];
    const float* Ug   = (const float*)d_in[6];
    const float* bg   = (const float*)d_in[7];
    const float* fcw  = (const float*)d_in[8];
    const float* fcb  = (const float*)d_in[9];
    float* out = (float*)d_out;

    float* hA      = (float*)d_ws;                   // [B][N][U]
    float* hB      = hA + (size_t)B * N * U;         // [B][N][U]
    float* partial = hB + (size_t)B * N * U;         // [B][16][NCLS]

    // steps 0-2: layer 0; steps 3-5: layer 1
    k_step<1, 0><<<B * 16, 256, 0, stream>>>(x, lens, nullptr, hA, A, Wmsg, bmsg, Wg, Ug, bg, fcw, partial, 0);
    k_step<0, 0><<<B * 16, 256, 0, stream>>>(x, lens, hA, hB, A, Wmsg, bmsg, Wg, Ug, bg, fcw, partial, 0);
    k_step<0, 0><<<B * 16, 256, 0, stream>>>(x, lens, hB, hA, A, Wmsg, bmsg, Wg, Ug, bg, fcw, partial, 0);
    k_step<0, 0><<<B * 16, 256, 0, stream>>>(x, lens, hA, hB, A, Wmsg, bmsg, Wg, Ug, bg, fcw, partial, 1);
    k_step<0, 0><<<B * 16, 256, 0, stream>>>(x, lens, hB, hA, A, Wmsg, bmsg, Wg, Ug, bg, fcw, partial, 1);
    k_step<0, 1><<<B * 16, 256, 0, stream>>>(x, lens, hA, hB, A, Wmsg, bmsg, Wg, Ug, bg, fcw, partial, 1);
    k_final<<<B, 64, 0, stream>>>(partial, fcb, out);
}